// Round 4
// baseline (448.279 us; speedup 1.0000x reference)
//
#include <hip/hip_runtime.h>
#include <hip/hip_bf16.h>
#include <stdint.h>

// Problem constants
#define Bq 1024
#define Dq 512
#define Nq 16
#define Hq 512
#define Mq (Bq*Nq)   // 16384

typedef short v8s  __attribute__((ext_vector_type(8)));
typedef float v4f  __attribute__((ext_vector_type(4)));
typedef float v16f __attribute__((ext_vector_type(16)));

typedef __attribute__((address_space(3))) unsigned int as3_u32;
typedef __attribute__((address_space(1))) const unsigned int as1_u32;

#define VMCNT(n) asm volatile("s_waitcnt vmcnt(" #n ")" ::: "memory")

__device__ __forceinline__ unsigned short f2bf(float f) {
  union { float f; unsigned u; } v; v.f = f;
  return (unsigned short)((v.u + 0x7fffu + ((v.u >> 16) & 1u)) >> 16);
}

// Xb[b*16+n][d] = bf16(x[b][d][n])
__global__ void k_transpose_x(const float* __restrict__ x, unsigned short* __restrict__ xb) {
  __shared__ float lds[Dq][Nq + 1];
  const int b = blockIdx.x;
  const float* xi = x + (size_t)b * Dq * Nq;
  const int t = threadIdx.x;
  for (int p = 0; p < (Dq*Nq)/256; ++p) {
    int i = t + p*256;
    lds[i >> 4][i & (Nq-1)] = xi[i];
  }
  __syncthreads();
  unsigned short* o = xb + (size_t)b * Nq * Dq;
  for (int p = 0; p < (Dq*Nq)/256; ++p) {
    int i = t + p*256;
    o[i] = f2bf(lds[i & (Dq-1)][i >> 9]);   // i = n*512 + d
  }
}

// One dispatch for all weight transposes: z=0 -> Ws1, z=1 -> Ws2, z>=2 -> Wc1[z-2]
__global__ void k_transpose_w(const float* __restrict__ Ws1, const float* __restrict__ Ws2,
                              const float* __restrict__ Wc1,
                              unsigned short* __restrict__ Ws1t, unsigned short* __restrict__ Ws2t,
                              unsigned short* __restrict__ Wc1t) {
  __shared__ float tile[32][33];
  const int z = blockIdx.z;
  const float* in;
  unsigned short* out;
  if (z == 0)      { in = Ws1; out = Ws1t; }
  else if (z == 1) { in = Ws2; out = Ws2t; }
  else             { in = Wc1 + (size_t)(z-2) * 512 * 512; out = Wc1t + (size_t)(z-2) * 512 * 512; }
  const int tx = threadIdx.x, ty = threadIdx.y;  // (32,8)
  const int c0 = blockIdx.x * 32, r0 = blockIdx.y * 32;
#pragma unroll
  for (int j = 0; j < 4; ++j)
    tile[ty + j*8][tx] = in[(size_t)(r0 + ty + j*8) * 512 + c0 + tx];
  __syncthreads();
#pragma unroll
  for (int j = 0; j < 4; ++j) {
    int c = c0 + ty + j*8;   // output row (input col)
    int r = r0 + tx;         // output col (input row)
    out[(size_t)c * 512 + r] = f2bf(tile[tx][ty + j*8]);
  }
}

// ---------------------------------------------------------------------------
// Old-structure GEMM, kept for the two shared-MLP GEMMs (MODE=0 only).
// ---------------------------------------------------------------------------
template<int MODE, int BM>
__global__ __launch_bounds__(256, 2)
void k_gemm(const unsigned short* __restrict__ A,
            const unsigned short* __restrict__ Bt,
            const float* __restrict__ bias,
            void* __restrict__ out_,
            const float* __restrict__ w2,
            int permute) {
  constexpr int BN = 128, BK = 32, KD = 512;
  constexpr int NI = (BM == 256) ? 4 : 2;
  constexpr int AG = BM / 16;
  constexpr int TG = AG + BN / 16;
  __shared__ __align__(16) unsigned short As[2][BM][BK];
  __shared__ __align__(16) unsigned short Bs[2][BN][BK];

  const int t = threadIdx.x;
  const int wave = t >> 6, lane = t & 63;
  const int wr = (BM == 256) ? wave : (wave >> 1);
  const int wc = (BM == 256) ? 0    : (wave & 1);
  const int l32 = lane & 31, kh0 = lane >> 5;
  const int bm = blockIdx.x * BM, bn = blockIdx.y * BN;
  const int z = blockIdx.z;

  const unsigned short* Bz = Bt + (size_t)z * KD * 512;
  const float* biasz = bias + (size_t)z * 512;

  const int lrow = lane >> 2;
  const int lslot = lane & 3;

  auto stage = [&](int buf, int kt) {
#pragma unroll
    for (int i = wave; i < TG; i += 4) {
      const int isA = (i < AG);
      const int r0 = (isA ? i : i - AG) * 16;
      const int row = r0 + lrow;
      const int cg = lslot ^ ((row >> 1) & 3);
      const unsigned short* g = isA ? &A [(size_t)(bm + row) * KD + kt*BK + cg*8]
                                    : &Bz[(size_t)(bn + row) * KD + kt*BK + cg*8];
      as3_u32* d = isA ? (as3_u32*)&As[buf][r0][0] : (as3_u32*)&Bs[buf][r0][0];
      __builtin_amdgcn_global_load_lds((as1_u32*)g, d, 16, 0, 0);
    }
  };

  v16f acc[2][NI] = {};

  stage(0, 0);
  __syncthreads();

  for (int kt = 0; kt < KD / BK; ++kt) {
    const int cur = kt & 1;
    if (kt + 1 < KD / BK) stage(cur ^ 1, kt + 1);

    v8s af[2][2], bf[NI][2];
#pragma unroll
    for (int mi = 0; mi < 2; ++mi) {
      int ra = wr*64 + mi*32 + l32;
#pragma unroll
      for (int kh = 0; kh < 2; ++kh) {
        int c = kh*2 + kh0;
        af[mi][kh] = *(const v8s*)&As[cur][ra][(c ^ ((ra >> 1) & 3)) * 8];
      }
    }
#pragma unroll
    for (int ni = 0; ni < NI; ++ni) {
      int rb = wc*64 + ni*32 + l32;
#pragma unroll
      for (int kh = 0; kh < 2; ++kh) {
        int c = kh*2 + kh0;
        bf[ni][kh] = *(const v8s*)&Bs[cur][rb][(c ^ ((rb >> 1) & 3)) * 8];
      }
    }
#pragma unroll
    for (int kh = 0; kh < 2; ++kh)
#pragma unroll
      for (int mi = 0; mi < 2; ++mi)
#pragma unroll
        for (int ni = 0; ni < NI; ++ni)
          acc[mi][ni] = __builtin_amdgcn_mfma_f32_32x32x16_bf16(af[mi][kh], bf[ni][kh], acc[mi][ni], 0, 0, 0);
    __syncthreads();
  }

  if (MODE == 0) {
    unsigned short* O = (unsigned short*)out_;
#pragma unroll
    for (int mi = 0; mi < 2; ++mi) {
#pragma unroll
      for (int ni = 0; ni < NI; ++ni) {
        int col = bn + wc*64 + ni*32 + l32;
        float bcol = biasz[col];
#pragma unroll
        for (int reg = 0; reg < 16; ++reg) {
          int rl = (reg & 3) + 8*(reg >> 2) + 4*kh0;
          int grow = bm + wr*64 + mi*32 + rl;
          int orow = permute ? ((grow & 15) * Bq + (grow >> 4)) : grow;
          float v = acc[mi][ni][reg] + bcol;
          v = v >= 0.f ? v : 0.1f * v;
          O[(size_t)orow * 512 + col] = f2bf(v);
        }
      }
    }
  } else {
    float* FL = (float*)out_;
    const float* w2z = w2 + (size_t)z * 512;
#pragma unroll
    for (int mi = 0; mi < 2; ++mi) {
#pragma unroll
      for (int reg = 0; reg < 16; ++reg) {
        int rl = (reg & 3) + 8*(reg >> 2) + 4*kh0;
        float s = 0.f;
#pragma unroll
        for (int ni = 0; ni < NI; ++ni) {
          int col = bn + ni*32 + l32;
          float v = acc[mi][ni][reg] + biasz[col];
          v = v >= 0.f ? v : 0.1f * v;
          s += v * w2z[col];
        }
#pragma unroll
        for (int off = 1; off < 32; off <<= 1)
          s += __shfl_xor(s, off, 64);
        if (l32 == 0) {
          int grow = bm + wave*64 + mi*32 + rl;
          atomicAdd(&FL[(size_t)grow * Nq + z], s);
        }
      }
    }
  }
}

// ---------------------------------------------------------------------------
// Head-GEMM v4: 256x128 block, 256 threads = 4 waves, per-wave 128x64 output
// via 32x32x16 MFMA (acc[4][2] v16f = 128 VGPR; 12 wave-b128 reads per 16
// MFMA-32 -> LDS floor ~61us < MFMA floor ~55-66us).  Ring-3 LDS 72 KiB ->
// 2 blocks/CU (cross-block MFMA/LDS overlap), ONE barrier + one counted
// VMCNT(6) per K-tile.  NATURAL dispatch order (x=bm fastest, z slowest) --
// R3's manual XCD swizzle destroyed L2/L3 locality (FETCH 41->530 MB).
// Proven chunk-XOR swizzle c ^ ((row>>1)&3) on staging source and reads.
// ---------------------------------------------------------------------------
__global__ __launch_bounds__(256, 2)
void k_headgemm(const unsigned short* __restrict__ A,
                const unsigned short* __restrict__ Bt,
                const float* __restrict__ bias,
                float* __restrict__ FL,
                const float* __restrict__ w2) {
  __shared__ __align__(16) unsigned short As[3][256][32];
  __shared__ __align__(16) unsigned short Bs[3][128][32];

  const int t = threadIdx.x;
  const int wave = t >> 6, lane = t & 63;
  const int wr = wave >> 1, wc = wave & 1;         // 2M x 2N of 128x64
  const int l32 = lane & 31, kh0 = lane >> 5;

  const int bm = blockIdx.x * 256;                 // x fastest: A-panel sharing
  const int bn = blockIdx.y * 128;
  const int z  = blockIdx.z;

  const unsigned short* Bz = Bt + (size_t)z * Dq * 512;
  const float* biasz = bias + (size_t)z * 512;
  const float* w2z   = w2   + (size_t)z * 512;

  // Staging: per K-tile, wave covers A rows [wave*64,+64) (4 x 1KB issues)
  // and B rows [wave*32,+32) (2 x 1KB issues) = 6 gload_lds per wave.
  const int sr = lane >> 2;                        // row within 16-row group
  const int sc = (lane & 3) ^ ((sr >> 1) & 3);     // inverse-swizzled chunk
  const unsigned short* aSrc = A  + (size_t)(bm + wave*64 + sr) * Dq + sc*8;
  const unsigned short* bSrc = Bz + (size_t)(bn + wave*32 + sr) * Dq + sc*8;
  char* dstA = (char*)As + (wave*64) * 64;
  char* dstB = (char*)Bs + (wave*32) * 64;

  auto stage = [&](int T, int slot) {
    if (T >= 16) return;
#pragma unroll
    for (int j = 0; j < 4; ++j)
      __builtin_amdgcn_global_load_lds((as1_u32*)(aSrc + T*32 + (size_t)j*16*Dq),
                                       (as3_u32*)(dstA + slot*16384 + j*1024), 16, 0, 0);
#pragma unroll
    for (int j = 0; j < 2; ++j)
      __builtin_amdgcn_global_load_lds((as1_u32*)(bSrc + T*32 + (size_t)j*16*Dq),
                                       (as3_u32*)(dstB + slot*8192 + j*1024), 16, 0, 0);
  };

  // Fragment read offsets (bytes within one slot), 32x32x16 layout:
  // row = base + l32, chunk c = kh*2 + kh0, slot chunk = c ^ ((row>>1)&3).
  int offA[4][2], offB[2][2];
#pragma unroll
  for (int mi = 0; mi < 4; ++mi) {
    int ra = wr*128 + mi*32 + l32;
#pragma unroll
    for (int kh = 0; kh < 2; ++kh)
      offA[mi][kh] = ra*64 + (((kh*2 + kh0) ^ ((ra >> 1) & 3)) * 16);
  }
#pragma unroll
  for (int ni = 0; ni < 2; ++ni) {
    int rb = wc*64 + ni*32 + l32;
#pragma unroll
    for (int kh = 0; kh < 2; ++kh)
      offB[ni][kh] = rb*64 + (((kh*2 + kh0) ^ ((rb >> 1) & 3)) * 16);
  }

  v16f acc[4][2] = {};

  // Prologue: prefetch tiles 0 (slot 0) and 1 (slot 1).
  stage(0, 0);
  stage(1, 1);
  VMCNT(6);                       // tile 0 landed; tile 1 (6/wave) in flight
  __builtin_amdgcn_s_barrier();
  __builtin_amdgcn_sched_barrier(0);

  int sR = 0, sS = 2;
  for (int kt = 0; kt < 16; ++kt) {
    stage(kt + 2, sS);            // write slot disjoint from read slot (ring-3)

    const char* aB = (const char*)As + sR * 16384;
    const char* bB = (const char*)Bs + sR * 8192;
    v8s af[4][2], bf[2][2];
#pragma unroll
    for (int mi = 0; mi < 4; ++mi)
#pragma unroll
      for (int kh = 0; kh < 2; ++kh)
        af[mi][kh] = *(const v8s*)(aB + offA[mi][kh]);
#pragma unroll
    for (int ni = 0; ni < 2; ++ni)
#pragma unroll
      for (int kh = 0; kh < 2; ++kh)
        bf[ni][kh] = *(const v8s*)(bB + offB[ni][kh]);

    __builtin_amdgcn_s_setprio(1);
#pragma unroll
    for (int kh = 0; kh < 2; ++kh)
#pragma unroll
      for (int mi = 0; mi < 4; ++mi)
#pragma unroll
        for (int ni = 0; ni < 2; ++ni)
          acc[mi][ni] = __builtin_amdgcn_mfma_f32_32x32x16_bf16(af[mi][kh], bf[ni][kh], acc[mi][ni], 0, 0, 0);
    __builtin_amdgcn_s_setprio(0);

    // Counted drain: stage(kt+1) must have landed before next phase reads it;
    // stage(kt+2)'s 6 issues stay in flight (never vmcnt(0) mid-loop).
    if (kt < 14)       { VMCNT(6); }
    else if (kt == 14) { VMCNT(0); }
    if (kt < 15) {
      __builtin_amdgcn_s_barrier();
      __builtin_amdgcn_sched_barrier(0);
    }
    sR = (sR + 1 == 3) ? 0 : sR + 1;
    sS = (sS + 1 == 3) ? 0 : sS + 1;
  }

  // Epilogue: lrelu + Wc2 dot over this wave's 64 cols, 32-lane reduce,
  // atomicAdd partial into FL[m][z].  32x32 D-frag: col=l32,
  // row=(reg&3)+8*(reg>>2)+4*kh0.
  float bcol[2], wcol[2];
#pragma unroll
  for (int ni = 0; ni < 2; ++ni) {
    int col = bn + wc*64 + ni*32 + l32;
    bcol[ni] = biasz[col];
    wcol[ni] = w2z[col];
  }
#pragma unroll
  for (int mi = 0; mi < 4; ++mi) {
#pragma unroll
    for (int reg = 0; reg < 16; ++reg) {
      int rl = (reg & 3) + 8*(reg >> 2) + 4*kh0;
      float s = 0.f;
#pragma unroll
      for (int ni = 0; ni < 2; ++ni) {
        float v = acc[mi][ni][reg] + bcol[ni];
        v = v >= 0.f ? v : 0.1f * v;
        s += v * wcol[ni];
      }
#pragma unroll
      for (int off = 1; off < 32; off <<= 1)
        s += __shfl_xor(s, off, 64);
      if (l32 == 0) {
        int grow = bm + wr*128 + mi*32 + rl;
        atomicAdd(&FL[(size_t)grow * Nq + z], s);
      }
    }
  }
}

// full_out[m][n] = FL[m][n] + bc2[n]; out[b][n] = sigmoid(full_out[n*B+b][n])
__global__ void k_final(const float* __restrict__ fl, const float* __restrict__ bc2,
                        float* __restrict__ out) {
  int i = blockIdx.x * 256 + threadIdx.x;
  int m = i >> 4, n = i & 15;
  float v = fl[i] + bc2[n];
  out[Mq + i] = v;
  if (n == (m >> 10)) {
    int b = m & (Bq - 1);
    out[b * Nq + n] = 1.f / (1.f + __expf(-v));
  }
}

extern "C" void kernel_launch(void* const* d_in, const int* in_sizes, int n_in,
                              void* d_out, int out_size, void* d_ws, size_t ws_size,
                              hipStream_t stream) {
  (void)in_sizes; (void)n_in; (void)out_size; (void)ws_size;
  const float* x   = (const float*)d_in[0];
  const float* Ws1 = (const float*)d_in[1];
  const float* bs1 = (const float*)d_in[2];
  const float* Ws2 = (const float*)d_in[3];
  const float* bs2 = (const float*)d_in[4];
  const float* Wc1 = (const float*)d_in[5];
  const float* bc1 = (const float*)d_in[6];
  const float* Wc2 = (const float*)d_in[7];
  const float* bc2 = (const float*)d_in[8];

  char* ws = (char*)d_ws;
  unsigned short* Xb   = (unsigned short*)(ws);
  unsigned short* Hbuf = (unsigned short*)(ws + (size_t)16*1024*1024);
  unsigned short* Sm   = (unsigned short*)(ws + (size_t)32*1024*1024);
  unsigned short* Ws1t = (unsigned short*)(ws + (size_t)48*1024*1024);
  unsigned short* Ws2t = (unsigned short*)(ws + (size_t)48*1024*1024 + 512*1024);
  unsigned short* Wc1t = (unsigned short*)(ws + (size_t)49*1024*1024);
  float*          FL   = (float*)         (ws + (size_t)57*1024*1024);

  hipMemsetAsync(FL, 0, (size_t)Mq * Nq * sizeof(float), stream);

  k_transpose_x<<<Bq, 256, 0, stream>>>(x, Xb);
  k_transpose_w<<<dim3(16,16,18), dim3(32,8), 0, stream>>>(Ws1, Ws2, Wc1, Ws1t, Ws2t, Wc1t);

  // shared MLP: H = lrelu(Xb@Ws1+bs1); Sm = lrelu(H@Ws2+bs2) in m = n*B+b row order
  k_gemm<0,128><<<dim3(128,4,1), 256, 0, stream>>>(Xb,   Ws1t, bs1, Hbuf, nullptr, 0);
  k_gemm<0,128><<<dim3(128,4,1), 256, 0, stream>>>(Hbuf, Ws2t, bs2, Sm,   nullptr, 1);
  // fused per-head GEMM + H-reduction into FL (ring-3, natural dispatch order)
  k_headgemm<<<dim3(64,4,16), 256, 0, stream>>>(Sm, Wc1t, bc1, FL, Wc2);

  k_final<<<(Mq*Nq)/256, 256, 0, stream>>>(FL, bc2, (float*)d_out);
}

// Round 5
// 321.194 us; speedup vs baseline: 1.3957x; 1.3957x over previous
//
#include <hip/hip_runtime.h>
#include <hip/hip_bf16.h>
#include <stdint.h>

// Problem constants
#define Bq 1024
#define Dq 512
#define Nq 16
#define Hq 512
#define Mq (Bq*Nq)   // 16384

typedef short v8s  __attribute__((ext_vector_type(8)));
typedef float v4f  __attribute__((ext_vector_type(4)));
typedef float v16f __attribute__((ext_vector_type(16)));

typedef __attribute__((address_space(3))) unsigned int as3_u32;
typedef __attribute__((address_space(1))) const unsigned int as1_u32;

__device__ __forceinline__ unsigned short f2bf(float f) {
  union { float f; unsigned u; } v; v.f = f;
  return (unsigned short)((v.u + 0x7fffu + ((v.u >> 16) & 1u)) >> 16);
}

// Xb[b*16+n][d] = bf16(x[b][d][n])
__global__ void k_transpose_x(const float* __restrict__ x, unsigned short* __restrict__ xb) {
  __shared__ float lds[Dq][Nq + 1];
  const int b = blockIdx.x;
  const float* xi = x + (size_t)b * Dq * Nq;
  const int t = threadIdx.x;
  for (int p = 0; p < (Dq*Nq)/256; ++p) {
    int i = t + p*256;
    lds[i >> 4][i & (Nq-1)] = xi[i];
  }
  __syncthreads();
  unsigned short* o = xb + (size_t)b * Nq * Dq;
  for (int p = 0; p < (Dq*Nq)/256; ++p) {
    int i = t + p*256;
    o[i] = f2bf(lds[i & (Dq-1)][i >> 9]);   // i = n*512 + d
  }
}

// One dispatch for all weight transposes: z=0 -> Ws1, z=1 -> Ws2, z>=2 -> Wc1[z-2]
__global__ void k_transpose_w(const float* __restrict__ Ws1, const float* __restrict__ Ws2,
                              const float* __restrict__ Wc1,
                              unsigned short* __restrict__ Ws1t, unsigned short* __restrict__ Ws2t,
                              unsigned short* __restrict__ Wc1t) {
  __shared__ float tile[32][33];
  const int z = blockIdx.z;
  const float* in;
  unsigned short* out;
  if (z == 0)      { in = Ws1; out = Ws1t; }
  else if (z == 1) { in = Ws2; out = Ws2t; }
  else             { in = Wc1 + (size_t)(z-2) * 512 * 512; out = Wc1t + (size_t)(z-2) * 512 * 512; }
  const int tx = threadIdx.x, ty = threadIdx.y;  // (32,8)
  const int c0 = blockIdx.x * 32, r0 = blockIdx.y * 32;
#pragma unroll
  for (int j = 0; j < 4; ++j)
    tile[ty + j*8][tx] = in[(size_t)(r0 + ty + j*8) * 512 + c0 + tx];
  __syncthreads();
#pragma unroll
  for (int j = 0; j < 4; ++j) {
    int c = c0 + ty + j*8;   // output row (input col)
    int r = r0 + tx;         // output col (input row)
    out[(size_t)c * 512 + r] = f2bf(tile[tx][ty + j*8]);
  }
}

// ---------------------------------------------------------------------------
// Old-structure GEMM, kept for the two shared-MLP GEMMs (MODE=0 only).
// ---------------------------------------------------------------------------
template<int MODE, int BM>
__global__ __launch_bounds__(256, 2)
void k_gemm(const unsigned short* __restrict__ A,
            const unsigned short* __restrict__ Bt,
            const float* __restrict__ bias,
            void* __restrict__ out_,
            const float* __restrict__ w2,
            int permute) {
  constexpr int BN = 128, BK = 32, KD = 512;
  constexpr int NI = (BM == 256) ? 4 : 2;
  constexpr int AG = BM / 16;
  constexpr int TG = AG + BN / 16;
  __shared__ __align__(16) unsigned short As[2][BM][BK];
  __shared__ __align__(16) unsigned short Bs[2][BN][BK];

  const int t = threadIdx.x;
  const int wave = t >> 6, lane = t & 63;
  const int wr = (BM == 256) ? wave : (wave >> 1);
  const int wc = (BM == 256) ? 0    : (wave & 1);
  const int l32 = lane & 31, kh0 = lane >> 5;
  const int bm = blockIdx.x * BM, bn = blockIdx.y * BN;
  const int z = blockIdx.z;

  const unsigned short* Bz = Bt + (size_t)z * KD * 512;
  const float* biasz = bias + (size_t)z * 512;

  const int lrow = lane >> 2;
  const int lslot = lane & 3;

  auto stage = [&](int buf, int kt) {
#pragma unroll
    for (int i = wave; i < TG; i += 4) {
      const int isA = (i < AG);
      const int r0 = (isA ? i : i - AG) * 16;
      const int row = r0 + lrow;
      const int cg = lslot ^ ((row >> 1) & 3);
      const unsigned short* g = isA ? &A [(size_t)(bm + row) * KD + kt*BK + cg*8]
                                    : &Bz[(size_t)(bn + row) * KD + kt*BK + cg*8];
      as3_u32* d = isA ? (as3_u32*)&As[buf][r0][0] : (as3_u32*)&Bs[buf][r0][0];
      __builtin_amdgcn_global_load_lds((as1_u32*)g, d, 16, 0, 0);
    }
  };

  v16f acc[2][NI] = {};

  stage(0, 0);
  __syncthreads();

  for (int kt = 0; kt < KD / BK; ++kt) {
    const int cur = kt & 1;
    if (kt + 1 < KD / BK) stage(cur ^ 1, kt + 1);

    v8s af[2][2], bf[NI][2];
#pragma unroll
    for (int mi = 0; mi < 2; ++mi) {
      int ra = wr*64 + mi*32 + l32;
#pragma unroll
      for (int kh = 0; kh < 2; ++kh) {
        int c = kh*2 + kh0;
        af[mi][kh] = *(const v8s*)&As[cur][ra][(c ^ ((ra >> 1) & 3)) * 8];
      }
    }
#pragma unroll
    for (int ni = 0; ni < NI; ++ni) {
      int rb = wc*64 + ni*32 + l32;
#pragma unroll
      for (int kh = 0; kh < 2; ++kh) {
        int c = kh*2 + kh0;
        bf[ni][kh] = *(const v8s*)&Bs[cur][rb][(c ^ ((rb >> 1) & 3)) * 8];
      }
    }
#pragma unroll
    for (int kh = 0; kh < 2; ++kh)
#pragma unroll
      for (int mi = 0; mi < 2; ++mi)
#pragma unroll
        for (int ni = 0; ni < NI; ++ni)
          acc[mi][ni] = __builtin_amdgcn_mfma_f32_32x32x16_bf16(af[mi][kh], bf[ni][kh], acc[mi][ni], 0, 0, 0);
    __syncthreads();
  }

  if (MODE == 0) {
    unsigned short* O = (unsigned short*)out_;
#pragma unroll
    for (int mi = 0; mi < 2; ++mi) {
#pragma unroll
      for (int ni = 0; ni < NI; ++ni) {
        int col = bn + wc*64 + ni*32 + l32;
        float bcol = biasz[col];
#pragma unroll
        for (int reg = 0; reg < 16; ++reg) {
          int rl = (reg & 3) + 8*(reg >> 2) + 4*kh0;
          int grow = bm + wr*64 + mi*32 + rl;
          int orow = permute ? ((grow & 15) * Bq + (grow >> 4)) : grow;
          float v = acc[mi][ni][reg] + bcol;
          v = v >= 0.f ? v : 0.1f * v;
          O[(size_t)orow * 512 + col] = f2bf(v);
        }
      }
    }
  } else {
    float* FL = (float*)out_;
    const float* w2z = w2 + (size_t)z * 512;
#pragma unroll
    for (int mi = 0; mi < 2; ++mi) {
#pragma unroll
      for (int reg = 0; reg < 16; ++reg) {
        int rl = (reg & 3) + 8*(reg >> 2) + 4*kh0;
        float s = 0.f;
#pragma unroll
        for (int ni = 0; ni < NI; ++ni) {
          int col = bn + ni*32 + l32;
          float v = acc[mi][ni][reg] + biasz[col];
          v = v >= 0.f ? v : 0.1f * v;
          s += v * w2z[col];
        }
#pragma unroll
        for (int off = 1; off < 32; off <<= 1)
          s += __shfl_xor(s, off, 64);
        if (l32 == 0) {
          int grow = bm + wave*64 + mi*32 + rl;
          atomicAdd(&FL[(size_t)grow * Nq + z], s);
        }
      }
    }
  }
}

// ---------------------------------------------------------------------------
// Head-GEMM v5: exact m97 geometry (the guide's verified 36%-of-peak recipe).
// 128x128 tile, 256 threads = 4 waves of 64x64 (acc[4][4] v4f = 64 regs ->
// ~12 waves/CU, cross-block overlap hides the barrier drain per m114).
// BK=64, SINGLE-buffered LDS As[128][64]+Bs[128][64] = 32 KiB.
// 128-B rows: chunk(16B) swizzle  c ^= (row&7)  -> uniform 8 words/bank for
// the 16x16x32 fragment b128 reads (the zero-conflict class: R2/R3 measured 0).
// Staging: global_load_lds width-16, linear LDS dest, inverse-swizzled source.
// Plain 2-barrier K-loop (8 steps), no setprio/sched_barrier/counted-vmcnt.
// Natural dispatch order (x=bm fastest) -- R3 showed manual swizzles thrash L2.
// ---------------------------------------------------------------------------
__global__ __launch_bounds__(256)
void k_headgemm(const unsigned short* __restrict__ A,
                const unsigned short* __restrict__ Bt,
                const float* __restrict__ bias,
                float* __restrict__ FL,
                const float* __restrict__ w2) {
  __shared__ __align__(16) unsigned short As[128][64];
  __shared__ __align__(16) unsigned short Bs[128][64];

  const int t = threadIdx.x;
  const int wave = t >> 6, lane = t & 63;
  const int wr = wave >> 1, wc = wave & 1;         // 2x2 waves of 64x64
  const int fr = lane & 15, fq = lane >> 4;        // 16x16x32 frag coords

  const int bm = blockIdx.x * 128;                 // x fastest: A-panel sharing
  const int bn = blockIdx.y * 128;
  const int z  = blockIdx.z;

  const unsigned short* Bz = Bt + (size_t)z * Dq * 512;
  const float* biasz = bias + (size_t)z * 512;
  const float* w2z   = w2   + (size_t)z * 512;

  // Staging: per K-step each wave covers A rows [wave*32,+32) and B rows
  // [wave*32,+32) as 4+4 issues of 1 KB (8 rows x 128 B each).
  // gload_lds dest is linear: lane l -> row l>>3, chunk l&7.  The read-side
  // swizzle is chunk^(row&7), so the SOURCE chunk must be pre-swizzled.
  const int sr8 = lane >> 3;                       // row within 8-row group
  const int sc8 = (lane & 7) ^ sr8;                // inverse-swizzled chunk
  const unsigned short* aSrc = A  + (size_t)(bm + wave*32 + sr8) * Dq + sc8*8;
  const unsigned short* bSrc = Bz + (size_t)(bn + wave*32 + sr8) * Dq + sc8*8;

  auto stage = [&](int kt) {
#pragma unroll
    for (int g = 0; g < 4; ++g)
      __builtin_amdgcn_global_load_lds((as1_u32*)(aSrc + kt*64 + (size_t)g*8*Dq),
                                       (as3_u32*)&As[wave*32 + g*8][0], 16, 0, 0);
#pragma unroll
    for (int g = 0; g < 4; ++g)
      __builtin_amdgcn_global_load_lds((as1_u32*)(bSrc + kt*64 + (size_t)g*8*Dq),
                                       (as3_u32*)&Bs[wave*32 + g*8][0], 16, 0, 0);
  };

  // Fragment byte offsets: row r, k-half kh -> chunk (kh*4+fq) ^ (r&7).
  // r&7 == fr&7 (row bases are multiples of 16).
  int offA[4][2], offB[4][2];
#pragma unroll
  for (int mi = 0; mi < 4; ++mi) {
    int r = wr*64 + mi*16 + fr;
#pragma unroll
    for (int kh = 0; kh < 2; ++kh)
      offA[mi][kh] = r*128 + (((kh*4 + fq) ^ (fr & 7)) * 16);
  }
#pragma unroll
  for (int ni = 0; ni < 4; ++ni) {
    int r = wc*64 + ni*16 + fr;
#pragma unroll
    for (int kh = 0; kh < 2; ++kh)
      offB[ni][kh] = r*128 + (((kh*4 + fq) ^ (fr & 7)) * 16);
  }

  v4f acc[4][4] = {};

  for (int kt = 0; kt < 8; ++kt) {
    stage(kt);
    __syncthreads();               // drains vmcnt -> staged data visible

#pragma unroll
    for (int kh = 0; kh < 2; ++kh) {
      v8s af[4], bf[4];
#pragma unroll
      for (int mi = 0; mi < 4; ++mi) af[mi] = *(const v8s*)((const char*)As + offA[mi][kh]);
#pragma unroll
      for (int ni = 0; ni < 4; ++ni) bf[ni] = *(const v8s*)((const char*)Bs + offB[ni][kh]);
#pragma unroll
      for (int mi = 0; mi < 4; ++mi)
#pragma unroll
        for (int ni = 0; ni < 4; ++ni)
          acc[mi][ni] = __builtin_amdgcn_mfma_f32_16x16x32_bf16(af[mi], bf[ni], acc[mi][ni], 0, 0, 0);
    }
    __syncthreads();               // all reads done before next stage overwrites
  }

  // Epilogue: lrelu + Wc2 dot over this wave's 64 cols, 16-lane reduce,
  // atomicAdd partial into FL[m][z].  D-frag: col=l&15, row=(l>>4)*4+reg.
  float bcol[4], wcol[4];
#pragma unroll
  for (int ni = 0; ni < 4; ++ni) {
    int col = bn + wc*64 + ni*16 + fr;
    bcol[ni] = biasz[col];
    wcol[ni] = w2z[col];
  }
#pragma unroll
  for (int mi = 0; mi < 4; ++mi) {
#pragma unroll
    for (int reg = 0; reg < 4; ++reg) {
      float s = 0.f;
#pragma unroll
      for (int ni = 0; ni < 4; ++ni) {
        float v = acc[mi][ni][reg] + bcol[ni];
        v = v >= 0.f ? v : 0.1f * v;
        s += v * wcol[ni];
      }
#pragma unroll
      for (int off = 1; off < 16; off <<= 1)
        s += __shfl_xor(s, off, 64);
      if (fr == 0) {
        int grow = bm + wr*64 + mi*16 + fq*4 + reg;
        atomicAdd(&FL[(size_t)grow * Nq + z], s);
      }
    }
  }
}

// full_out[m][n] = FL[m][n] + bc2[n]; out[b][n] = sigmoid(full_out[n*B+b][n])
__global__ void k_final(const float* __restrict__ fl, const float* __restrict__ bc2,
                        float* __restrict__ out) {
  int i = blockIdx.x * 256 + threadIdx.x;
  int m = i >> 4, n = i & 15;
  float v = fl[i] + bc2[n];
  out[Mq + i] = v;
  if (n == (m >> 10)) {
    int b = m & (Bq - 1);
    out[b * Nq + n] = 1.f / (1.f + __expf(-v));
  }
}

extern "C" void kernel_launch(void* const* d_in, const int* in_sizes, int n_in,
                              void* d_out, int out_size, void* d_ws, size_t ws_size,
                              hipStream_t stream) {
  (void)in_sizes; (void)n_in; (void)out_size; (void)ws_size;
  const float* x   = (const float*)d_in[0];
  const float* Ws1 = (const float*)d_in[1];
  const float* bs1 = (const float*)d_in[2];
  const float* Ws2 = (const float*)d_in[3];
  const float* bs2 = (const float*)d_in[4];
  const float* Wc1 = (const float*)d_in[5];
  const float* bc1 = (const float*)d_in[6];
  const float* Wc2 = (const float*)d_in[7];
  const float* bc2 = (const float*)d_in[8];

  char* ws = (char*)d_ws;
  unsigned short* Xb   = (unsigned short*)(ws);
  unsigned short* Hbuf = (unsigned short*)(ws + (size_t)16*1024*1024);
  unsigned short* Sm   = (unsigned short*)(ws + (size_t)32*1024*1024);
  unsigned short* Ws1t = (unsigned short*)(ws + (size_t)48*1024*1024);
  unsigned short* Ws2t = (unsigned short*)(ws + (size_t)48*1024*1024 + 512*1024);
  unsigned short* Wc1t = (unsigned short*)(ws + (size_t)49*1024*1024);
  float*          FL   = (float*)         (ws + (size_t)57*1024*1024);

  hipMemsetAsync(FL, 0, (size_t)Mq * Nq * sizeof(float), stream);

  k_transpose_x<<<Bq, 256, 0, stream>>>(x, Xb);
  k_transpose_w<<<dim3(16,16,18), dim3(32,8), 0, stream>>>(Ws1, Ws2, Wc1, Ws1t, Ws2t, Wc1t);

  // shared MLP: H = lrelu(Xb@Ws1+bs1); Sm = lrelu(H@Ws2+bs2) in m = n*B+b row order
  k_gemm<0,128><<<dim3(128,4,1), 256, 0, stream>>>(Xb,   Ws1t, bs1, Hbuf, nullptr, 0);
  k_gemm<0,128><<<dim3(128,4,1), 256, 0, stream>>>(Hbuf, Ws2t, bs2, Sm,   nullptr, 1);
  // fused per-head GEMM + H-reduction into FL (m97 geometry, 12 waves/CU)
  k_headgemm<<<dim3(128,4,16), 256, 0, stream>>>(Sm, Wc1t, bc1, FL, Wc2);

  k_final<<<(Mq*Nq)/256, 256, 0, stream>>>(FL, bc2, (float*)d_out);
}